// Round 1
// baseline (13011.201 us; speedup 1.0000x reference)
//
#include <hip/hip_runtime.h>
#include <math.h>

#define N_NODES 10000
#define D_IN    512
#define D_H     256
#define NCLS    40
#define NEDGE   160000
#define KTOP    16
#define CS      13            // column splits for sim kernel
#define BM      128
#define BN      128
#define KC      32
#define RB      ((N_NODES + BM - 1) / BM)   // 79
#define CTILES  ((N_NODES + BN - 1) / BN)   // 79

// ---------------- transpose weights ----------------
__global__ void transpose_kernel(const float* __restrict__ W1_l, const float* __restrict__ W1_r,
                                 const float* __restrict__ W2_l, const float* __restrict__ W2_r,
                                 float* __restrict__ W1lT, float* __restrict__ W1rT,
                                 float* __restrict__ W2lT, float* __restrict__ W2rT) {
    int i = blockIdx.x * 256 + threadIdx.x;
    if (i < D_H * D_IN) {                      // W1: [256][512] -> [512][256]
        int r = i / D_IN, c = i % D_IN;
        W1lT[(size_t)c * D_H + r] = W1_l[i];
        W1rT[(size_t)c * D_H + r] = W1_r[i];
    }
    if (i < NCLS * D_H) {                      // W2: [40][256] -> [256][40]
        int r = i / D_H, c = i % D_H;
        W2lT[(size_t)c * NCLS + r] = W2_l[i];
        W2rT[(size_t)c * NCLS + r] = W2_r[i];
    }
}

// ---------------- degree count ----------------
__global__ void count_kernel(const int* __restrict__ dst, float* __restrict__ cnt) {
    int e = blockIdx.x * 256 + threadIdx.x;
    if (e < NEDGE) atomicAdd(&cnt[dst[e]], 1.0f);
}

// ---------------- scatter x[src] -> agg1[dst] ----------------
__global__ void scatter1_kernel(const float* __restrict__ x, const int* __restrict__ src,
                                const int* __restrict__ dst, float* __restrict__ agg1) {
    int idx = blockIdx.x * 256 + threadIdx.x;     // e*(512/4) + f4
    int e  = idx >> 7;
    int f  = (idx & 127) << 2;
    if (e >= NEDGE) return;
    int s = src[e], d = dst[e];
    float4 v = *(const float4*)&x[(size_t)s * D_IN + f];
    float* p = &agg1[(size_t)d * D_IN + f];
    atomicAdd(p + 0, v.x); atomicAdd(p + 1, v.y);
    atomicAdd(p + 2, v.z); atomicAdd(p + 3, v.w);
}

// ---------------- scatter h[src] -> agg2[dst] ----------------
__global__ void scatter2_kernel(const float* __restrict__ h, const int* __restrict__ src,
                                const int* __restrict__ dst, float* __restrict__ agg2) {
    int idx = blockIdx.x * 256 + threadIdx.x;     // e*(256/4) + f4
    int e  = idx >> 6;
    int f  = (idx & 63) << 2;
    if (e >= NEDGE) return;
    int s = src[e], d = dst[e];
    float4 v = *(const float4*)&h[(size_t)s * D_H + f];
    float* p = &agg2[(size_t)d * D_H + f];
    atomicAdd(p + 0, v.x); atomicAdd(p + 1, v.y);
    atomicAdd(p + 2, v.z); atomicAdd(p + 3, v.w);
}

// ---------------- h = elu(agg1/cnt @ W1_l^T + b1 + x @ W1_r^T) ----------------
__global__ __launch_bounds__(256) void hidden_kernel(const float* __restrict__ x,
        const float* __restrict__ agg1, const float* __restrict__ cnt,
        const float* __restrict__ W1lT, const float* __restrict__ W1rT,
        const float* __restrict__ b1, float* __restrict__ h) {
    __shared__ float sa[8][D_IN];
    __shared__ float sx[8][D_IN];
    int tid = threadIdx.x;
    int nb0 = blockIdx.x * 8;
    for (int nb = 0; nb < 8; nb++) {
        int n = nb0 + nb;
        if (tid < 128) {
            float4 v = make_float4(0.f, 0.f, 0.f, 0.f);
            if (n < N_NODES) {
                float inv = 1.0f / fmaxf(cnt[n], 1.0f);
                v = *(const float4*)&agg1[(size_t)n * D_IN + tid * 4];
                v.x *= inv; v.y *= inv; v.z *= inv; v.w *= inv;
            }
            *(float4*)&sa[nb][tid * 4] = v;
        } else {
            int t2 = tid - 128;
            float4 v = make_float4(0.f, 0.f, 0.f, 0.f);
            if (n < N_NODES) v = *(const float4*)&x[(size_t)n * D_IN + t2 * 4];
            *(float4*)&sx[nb][t2 * 4] = v;
        }
    }
    __syncthreads();
    int j = tid;   // output feature 0..255
    float acc[8] = {0.f,0.f,0.f,0.f,0.f,0.f,0.f,0.f};
    for (int i = 0; i < D_IN; i += 4) {
        float wl0 = W1lT[(size_t)(i + 0) * D_H + j];
        float wl1 = W1lT[(size_t)(i + 1) * D_H + j];
        float wl2 = W1lT[(size_t)(i + 2) * D_H + j];
        float wl3 = W1lT[(size_t)(i + 3) * D_H + j];
        float wr0 = W1rT[(size_t)(i + 0) * D_H + j];
        float wr1 = W1rT[(size_t)(i + 1) * D_H + j];
        float wr2 = W1rT[(size_t)(i + 2) * D_H + j];
        float wr3 = W1rT[(size_t)(i + 3) * D_H + j];
        #pragma unroll
        for (int nb = 0; nb < 8; nb++) {
            float4 a  = *(const float4*)&sa[nb][i];
            float4 xx = *(const float4*)&sx[nb][i];
            float t = acc[nb];
            t = fmaf(a.x,  wl0, t); t = fmaf(a.y,  wl1, t);
            t = fmaf(a.z,  wl2, t); t = fmaf(a.w,  wl3, t);
            t = fmaf(xx.x, wr0, t); t = fmaf(xx.y, wr1, t);
            t = fmaf(xx.z, wr2, t); t = fmaf(xx.w, wr3, t);
            acc[nb] = t;
        }
    }
    float bj = b1[j];
    for (int nb = 0; nb < 8; nb++) {
        int n = nb0 + nb;
        if (n < N_NODES) {
            float vv = acc[nb] + bj;
            h[(size_t)n * D_H + j] = vv > 0.0f ? vv : expm1f(vv);
        }
    }
}

// ---------------- en = h / max(||h||,eps); also copy h to output ----------------
__global__ void norm_kernel(const float* __restrict__ h, float* __restrict__ en,
                            float* __restrict__ outh) {
    int wid = threadIdx.x >> 6, lane = threadIdx.x & 63;
    int n = blockIdx.x * 4 + wid;
    if (n >= N_NODES) return;
    float4 v = *(const float4*)&h[(size_t)n * D_H + lane * 4];
    float ss = v.x * v.x + v.y * v.y + v.z * v.z + v.w * v.w;
    for (int o = 32; o; o >>= 1) ss += __shfl_xor(ss, o);
    float inv = 1.0f / fmaxf(sqrtf(ss), 1e-8f);
    *(float4*)&en[(size_t)n * D_H + lane * 4] = make_float4(v.x*inv, v.y*inv, v.z*inv, v.w*inv);
    *(float4*)&outh[(size_t)n * D_H + lane * 4] = v;
}

// ---------------- lc_ls = log_softmax(elu(agg2/cnt @ W2_l^T + b2 + h @ W2_r^T)) ----------------
__global__ void lc_kernel(const float* __restrict__ h, const float* __restrict__ agg2,
        const float* __restrict__ cnt, const float* __restrict__ W2lT,
        const float* __restrict__ W2rT, const float* __restrict__ b2,
        float* __restrict__ lcls) {
    __shared__ float sa[4][D_H];
    __shared__ float sh[4][D_H];
    int wid = threadIdx.x >> 6, lane = threadIdx.x & 63;
    int n = blockIdx.x * 4 + wid;
    bool valid = (n < N_NODES);
    if (valid) {
        float inv = 1.0f / fmaxf(cnt[n], 1.0f);
        float4 a = *(const float4*)&agg2[(size_t)n * D_H + lane * 4];
        a.x *= inv; a.y *= inv; a.z *= inv; a.w *= inv;
        *(float4*)&sa[wid][lane * 4] = a;
        float4 hh = *(const float4*)&h[(size_t)n * D_H + lane * 4];
        *(float4*)&sh[wid][lane * 4] = hh;
    }
    __syncthreads();
    int c = lane;
    float acc = 0.0f;
    if (valid && c < NCLS) {
        for (int i = 0; i < D_H; i++) {
            acc = fmaf(sa[wid][i], W2lT[(size_t)i * NCLS + c], acc);
            acc = fmaf(sh[wid][i], W2rT[(size_t)i * NCLS + c], acc);
        }
        acc += b2[c];
        acc = acc > 0.0f ? acc : expm1f(acc);
    }
    float v = (valid && c < NCLS) ? acc : -INFINITY;
    float m = v;
    for (int o = 32; o; o >>= 1) m = fmaxf(m, __shfl_xor(m, o));
    float ex = (valid && c < NCLS) ? expf(v - m) : 0.0f;
    float s = ex;
    for (int o = 32; o; o >>= 1) s += __shfl_xor(s, o);
    if (valid && c < NCLS) lcls[(size_t)n * NCLS + c] = v - m - logf(s);
}

// ---------------- fused sim GEMM + mask + online top-16 (partial, per column split) ----------------
__global__ __launch_bounds__(256, 2) void sim_kernel(const float* __restrict__ en,
        const float* __restrict__ mask, float* __restrict__ pv, int* __restrict__ pi) {
    __shared__ float As[KC][BM];
    __shared__ float Bs[KC][BN];
    __shared__ float s_tv[BM][KTOP];
    __shared__ int   s_ti[BM][KTOP];
    __shared__ float s_thr[BM];
    __shared__ int   s_thri[BM];

    const int tid = threadIdx.x;
    const int tx = tid & 15, ty = tid >> 4;
    const int rb = blockIdx.x / CS, cs = blockIdx.x % CS;
    const int rbase = rb * BM;
    const int g = (tid & 63) >> 4;   // 16-lane group within wave

    for (int i = tid; i < BM * KTOP; i += 256) {
        (&s_tv[0][0])[i] = -INFINITY;
        (&s_ti[0][0])[i] = 0x7FFFFFFF;
    }
    for (int i = tid; i < BM; i += 256) { s_thr[i] = -INFINITY; s_thri[i] = 0x7FFFFFFF; }

    for (int ct = cs; ct < CTILES; ct += CS) {
        const int cbase = ct * BN;
        float acc[8][8];
        #pragma unroll
        for (int i = 0; i < 8; i++)
            #pragma unroll
            for (int j = 0; j < 8; j++) acc[i][j] = 0.0f;

        for (int kc = 0; kc < D_H; kc += KC) {
            __syncthreads();
            #pragma unroll
            for (int u = 0; u < 4; u++) {
                int li = tid + u * 256;          // 0..1023
                int r = li >> 3;                 // 0..127
                int k = (li & 7) << 2;           // 0,4,...,28
                int gr = rbase + r;
                int gc = cbase + r;
                float4 va = make_float4(0.f,0.f,0.f,0.f);
                float4 vb = make_float4(0.f,0.f,0.f,0.f);
                if (gr < N_NODES) va = *(const float4*)&en[(size_t)gr * D_H + kc + k];
                if (gc < N_NODES) vb = *(const float4*)&en[(size_t)gc * D_H + kc + k];
                As[k + 0][r] = va.x; As[k + 1][r] = va.y; As[k + 2][r] = va.z; As[k + 3][r] = va.w;
                Bs[k + 0][r] = vb.x; Bs[k + 1][r] = vb.y; Bs[k + 2][r] = vb.z; Bs[k + 3][r] = vb.w;
            }
            __syncthreads();
            #pragma unroll 4
            for (int k = 0; k < KC; k++) {
                float a0[8], b0[8];
                *(float4*)&a0[0] = *(const float4*)&As[k][ty * 8];
                *(float4*)&a0[4] = *(const float4*)&As[k][ty * 8 + 4];
                *(float4*)&b0[0] = *(const float4*)&Bs[k][tx * 8];
                *(float4*)&b0[4] = *(const float4*)&Bs[k][tx * 8 + 4];
                #pragma unroll
                for (int i = 0; i < 8; i++)
                    #pragma unroll
                    for (int j = 0; j < 8; j++)
                        acc[i][j] = fmaf(a0[i], b0[j], acc[i][j]);
            }
        }

        // masked top-16 update
        #pragma unroll 1
        for (int i = 0; i < 8; i++) {
            const int rl = ty * 8 + i;
            const int r = rbase + rl;
            const int c0 = cbase + tx * 8;
            bool cok = (r < N_NODES) && (c0 + 8 <= N_NODES);  // N%8==0 -> all-or-nothing
            float vv[8]; int ci[8];
            float mm[8];
            if (cok) {
                const float* mp = &mask[(size_t)r * N_NODES + c0];
                float4 m0 = *(const float4*)mp;
                float4 m1 = *(const float4*)(mp + 4);
                mm[0]=m0.x; mm[1]=m0.y; mm[2]=m0.z; mm[3]=m0.w;
                mm[4]=m1.x; mm[5]=m1.y; mm[6]=m1.z; mm[7]=m1.w;
            }
            #pragma unroll
            for (int j = 0; j < 8; j++) {
                if (cok) { vv[j] = acc[i][j] * mm[j]; ci[j] = c0 + j; }
                else     { vv[j] = -INFINITY;         ci[j] = 0x7FFFFFFF; }
            }
            float thr = (r < N_NODES) ? s_thr[rl] : 0.0f;
            int  thri = (r < N_NODES) ? s_thri[rl] : 0;
            bool q = false;
            if (cok) {
                #pragma unroll
                for (int j = 0; j < 8; j++)
                    q |= (vv[j] > thr) || ((vv[j] == thr) && (ci[j] < thri));
            }
            unsigned long long b = __ballot(q);
            unsigned long long gb = (b >> (g * 16)) & 0xFFFFull;
            while (gb) {
                int lw = (int)__builtin_ctzll(gb);
                if (tx == lw) {
                    float* tv = s_tv[rl]; int* tp = s_ti[rl];
                    for (int j = 0; j < 8; j++) {
                        float v = vv[j]; int idx = ci[j];
                        int w = 0; float wv = tv[0]; int wi = tp[0];
                        for (int k2 = 1; k2 < KTOP; k2++) {
                            float a = tv[k2]; int bi = tp[k2];
                            if (a < wv || (a == wv && bi > wi)) { wv = a; wi = bi; w = k2; }
                        }
                        if (v > wv || (v == wv && idx < wi)) { tv[w] = v; tp[w] = idx; }
                    }
                    float wv = tv[0]; int wi = tp[0];
                    for (int k2 = 1; k2 < KTOP; k2++) {
                        float a = tv[k2]; int bi = tp[k2];
                        if (a < wv || (a == wv && bi > wi)) { wv = a; wi = bi; }
                    }
                    s_thr[rl] = wv; s_thri[rl] = wi;
                }
                gb &= gb - 1;
            }
        }
    }
    __syncthreads();
    for (int i2 = tid; i2 < BM * KTOP; i2 += 256) {
        int rl = i2 / KTOP, k = i2 % KTOP;
        int r = rbase + rl;
        if (r < N_NODES) {
            size_t o = ((size_t)r * CS + cs) * KTOP + k;
            pv[o] = s_tv[rl][k];
            pi[o] = s_ti[rl][k];
        }
    }
}

// ---------------- merge partial top-16 lists, label fusion, blend ----------------
__global__ void merge_kernel(const float* __restrict__ pv, const int* __restrict__ pi,
        const int* __restrict__ y, const float* __restrict__ lcls, float* __restrict__ out) {
    int wid = threadIdx.x >> 6, lane = threadIdx.x & 63;
    int r = blockIdx.x * 4 + wid;
    if (r >= N_NODES) return;
    const int TOT = CS * KTOP;   // 208
    float v[4]; int id[4];
    #pragma unroll
    for (int u = 0; u < 4; u++) {
        int e = lane + u * 64;
        if (e < TOT) { v[u] = pv[(size_t)r * TOT + e]; id[u] = pi[(size_t)r * TOT + e]; }
        else         { v[u] = -INFINITY;               id[u] = 0x7FFFFFFF; }
    }
    float fc = 0.0f;   // fused[lane] for lane < 40
    for (int t = 0; t < KTOP; t++) {
        float bv = v[0]; int bi = id[0]; int bu = 0;
        #pragma unroll
        for (int u = 1; u < 4; u++)
            if (v[u] > bv || (v[u] == bv && id[u] < bi)) { bv = v[u]; bi = id[u]; bu = u; }
        float rv = bv; int ri = bi;
        for (int o = 1; o < 64; o <<= 1) {
            float ov = __shfl_xor(rv, o); int oi = __shfl_xor(ri, o);
            if (ov > rv || (ov == rv && oi < ri)) { rv = ov; ri = oi; }
        }
        if (bv == rv && bi == ri) { v[bu] = -INFINITY; id[bu] = 0x7FFFFFFF; }
        int lbl = y[ri];
        if (lane == lbl) fc += expf(rv);
    }
    float f = (lane < NCLS) ? fc : -INFINITY;
    float m = f;
    for (int o = 32; o; o >>= 1) m = fmaxf(m, __shfl_xor(m, o));
    float ex = (lane < NCLS) ? expf(f - m) : 0.0f;
    float s = ex;
    for (int o = 32; o; o >>= 1) s += __shfl_xor(s, o);
    if (lane < NCLS)
        out[(size_t)r * NCLS + lane] = 0.5f * lcls[(size_t)r * NCLS + lane]
                                     + 0.5f * (f - m - logf(s));
}

extern "C" void kernel_launch(void* const* d_in, const int* in_sizes, int n_in,
                              void* d_out, int out_size, void* d_ws, size_t ws_size,
                              hipStream_t stream) {
    const float* x    = (const float*)d_in[0];
    const int*   ei   = (const int*)  d_in[1];
    const int*   y    = (const int*)  d_in[2];
    const float* mask = (const float*)d_in[3];
    const float* W1_l = (const float*)d_in[4];
    const float* b1   = (const float*)d_in[5];
    const float* W1_r = (const float*)d_in[6];
    const float* W2_l = (const float*)d_in[7];
    const float* b2   = (const float*)d_in[8];
    const float* W2_r = (const float*)d_in[9];

    float* out   = (float*)d_out;
    float* out_h = out + (size_t)N_NODES * NCLS;

    float* w    = (float*)d_ws;
    float* cnt  = w;                                     // 10240 (padded)
    float* agg1 = w + 10240;                             // N*512
    float* agg2 = agg1 + (size_t)N_NODES * D_IN;         // N*256
    float* h    = agg2 + (size_t)N_NODES * D_H;          // N*256
    float* en   = h    + (size_t)N_NODES * D_H;          // N*256
    float* lcls = en   + (size_t)N_NODES * D_H;          // N*40
    float* W1lT = lcls + (size_t)N_NODES * NCLS;         // 512*256
    float* W1rT = W1lT + (size_t)D_IN * D_H;
    float* W2lT = W1rT + (size_t)D_IN * D_H;             // 256*40
    float* W2rT = W2lT + (size_t)D_H * NCLS;
    float* pv   = W2rT + (size_t)D_H * NCLS;             // N*CS*16
    int*   pi   = (int*)(pv + (size_t)N_NODES * CS * KTOP);

    const int* src = ei;
    const int* dst = ei + NEDGE;

    // zero cnt + agg1 + agg2 (contiguous)
    size_t zbytes = (size_t)(10240 + (size_t)N_NODES * D_IN + (size_t)N_NODES * D_H) * sizeof(float);
    hipMemsetAsync(d_ws, 0, zbytes, stream);

    transpose_kernel<<<(D_H * D_IN + 255) / 256, 256, 0, stream>>>(
        W1_l, W1_r, W2_l, W2_r, W1lT, W1rT, W2lT, W2rT);
    count_kernel<<<(NEDGE + 255) / 256, 256, 0, stream>>>(dst, cnt);
    scatter1_kernel<<<NEDGE * (D_IN / 4) / 256, 256, 0, stream>>>(x, src, dst, agg1);
    hidden_kernel<<<(N_NODES + 7) / 8, 256, 0, stream>>>(x, agg1, cnt, W1lT, W1rT, b1, h);
    norm_kernel<<<(N_NODES + 3) / 4, 256, 0, stream>>>(h, en, out_h);
    scatter2_kernel<<<NEDGE * (D_H / 4) / 256, 256, 0, stream>>>(h, src, dst, agg2);
    lc_kernel<<<(N_NODES + 3) / 4, 256, 0, stream>>>(h, agg2, cnt, W2lT, W2rT, b2, lcls);
    sim_kernel<<<RB * CS, 256, 0, stream>>>(en, mask, pv, pi);
    merge_kernel<<<(N_NODES + 3) / 4, 256, 0, stream>>>(pv, pi, y, lcls, out);
}

// Round 4
// 2597.298 us; speedup vs baseline: 5.0095x; 5.0095x over previous
//
#include <hip/hip_runtime.h>
#include <math.h>

#define N_NODES 10000
#define D_IN    512
#define D_H     256
#define NCLS    40
#define NEDGE   160000
#define KTOP    16
#define NFRAG   625            // 10000 / 16 column fragments
#define CSPL    2              // column splits (blocks per row-tile)
#define NSTREAM 8              // CSPL * 4 waves
#define SLOTS   8              // per-lane-group top-8
#define CPR     (NSTREAM * 4 * SLOTS)   // candidates per row = 256

typedef __attribute__((ext_vector_type(8))) short bf16x8;
typedef __attribute__((ext_vector_type(4))) float f32x4;

// ---------------- transpose weights (R1-proven) ----------------
__global__ void transpose_kernel(const float* __restrict__ W1_l, const float* __restrict__ W1_r,
                                 const float* __restrict__ W2_l, const float* __restrict__ W2_r,
                                 float* __restrict__ W1lT, float* __restrict__ W1rT,
                                 float* __restrict__ W2lT, float* __restrict__ W2rT) {
    int i = blockIdx.x * 256 + threadIdx.x;
    if (i < D_H * D_IN) {
        int r = i / D_IN, c = i % D_IN;
        W1lT[(size_t)c * D_H + r] = W1_l[i];
        W1rT[(size_t)c * D_H + r] = W1_r[i];
    }
    if (i < NCLS * D_H) {
        int r = i / D_H, c = i % D_H;
        W2lT[(size_t)c * NCLS + r] = W2_l[i];
        W2rT[(size_t)c * NCLS + r] = W2_r[i];
    }
}

// ---------------- degree count (R1-proven, float) ----------------
__global__ void count_kernel(const int* __restrict__ dst, float* __restrict__ cnt) {
    int e = blockIdx.x * 256 + threadIdx.x;
    if (e < NEDGE) {
        int d = dst[e];
        d = (d >= 0 && d < N_NODES) ? d : 0;
        atomicAdd(&cnt[d], 1.0f);
    }
}

// ---------------- scatter x[src] -> agg1[dst] (R1-proven) ----------------
__global__ void scatter1_kernel(const float* __restrict__ x, const int* __restrict__ src,
                                const int* __restrict__ dst, float* __restrict__ agg1) {
    int idx = blockIdx.x * 256 + threadIdx.x;
    int e  = idx >> 7;
    int f  = (idx & 127) << 2;
    if (e >= NEDGE) return;
    int s = src[e], d = dst[e];
    s = (s >= 0 && s < N_NODES) ? s : 0;
    d = (d >= 0 && d < N_NODES) ? d : 0;
    float4 v = *(const float4*)&x[(size_t)s * D_IN + f];
    float* p = &agg1[(size_t)d * D_IN + f];
    atomicAdd(p + 0, v.x); atomicAdd(p + 1, v.y);
    atomicAdd(p + 2, v.z); atomicAdd(p + 3, v.w);
}

// ---------------- scatter h[src] -> agg2[dst] (R1-proven) ----------------
__global__ void scatter2_kernel(const float* __restrict__ h, const int* __restrict__ src,
                                const int* __restrict__ dst, float* __restrict__ agg2) {
    int idx = blockIdx.x * 256 + threadIdx.x;
    int e  = idx >> 6;
    int f  = (idx & 63) << 2;
    if (e >= NEDGE) return;
    int s = src[e], d = dst[e];
    s = (s >= 0 && s < N_NODES) ? s : 0;
    d = (d >= 0 && d < N_NODES) ? d : 0;
    float4 v = *(const float4*)&h[(size_t)s * D_H + f];
    float* p = &agg2[(size_t)d * D_H + f];
    atomicAdd(p + 0, v.x); atomicAdd(p + 1, v.y);
    atomicAdd(p + 2, v.z); atomicAdd(p + 3, v.w);
}

// ---------------- h = elu(agg1/cnt @ W1_l^T + b1 + x @ W1_r^T) (R1-proven) ----------------
__global__ __launch_bounds__(256) void hidden_kernel(const float* __restrict__ x,
        const float* __restrict__ agg1, const float* __restrict__ cnt,
        const float* __restrict__ W1lT, const float* __restrict__ W1rT,
        const float* __restrict__ b1, float* __restrict__ h) {
    __shared__ float sa[8][D_IN];
    __shared__ float sx[8][D_IN];
    int tid = threadIdx.x;
    int nb0 = blockIdx.x * 8;
    for (int nb = 0; nb < 8; nb++) {
        int n = nb0 + nb;
        if (tid < 128) {
            float4 v = make_float4(0.f, 0.f, 0.f, 0.f);
            if (n < N_NODES) {
                float inv = 1.0f / fmaxf(cnt[n], 1.0f);
                v = *(const float4*)&agg1[(size_t)n * D_IN + tid * 4];
                v.x *= inv; v.y *= inv; v.z *= inv; v.w *= inv;
            }
            *(float4*)&sa[nb][tid * 4] = v;
        } else {
            int t2 = tid - 128;
            float4 v = make_float4(0.f, 0.f, 0.f, 0.f);
            if (n < N_NODES) v = *(const float4*)&x[(size_t)n * D_IN + t2 * 4];
            *(float4*)&sx[nb][t2 * 4] = v;
        }
    }
    __syncthreads();
    int j = tid;
    float acc[8] = {0.f,0.f,0.f,0.f,0.f,0.f,0.f,0.f};
    for (int i = 0; i < D_IN; i += 4) {
        float wl0 = W1lT[(size_t)(i + 0) * D_H + j];
        float wl1 = W1lT[(size_t)(i + 1) * D_H + j];
        float wl2 = W1lT[(size_t)(i + 2) * D_H + j];
        float wl3 = W1lT[(size_t)(i + 3) * D_H + j];
        float wr0 = W1rT[(size_t)(i + 0) * D_H + j];
        float wr1 = W1rT[(size_t)(i + 1) * D_H + j];
        float wr2 = W1rT[(size_t)(i + 2) * D_H + j];
        float wr3 = W1rT[(size_t)(i + 3) * D_H + j];
        #pragma unroll
        for (int nb = 0; nb < 8; nb++) {
            float4 a  = *(const float4*)&sa[nb][i];
            float4 xx = *(const float4*)&sx[nb][i];
            float t = acc[nb];
            t = fmaf(a.x,  wl0, t); t = fmaf(a.y,  wl1, t);
            t = fmaf(a.z,  wl2, t); t = fmaf(a.w,  wl3, t);
            t = fmaf(xx.x, wr0, t); t = fmaf(xx.y, wr1, t);
            t = fmaf(xx.z, wr2, t); t = fmaf(xx.w, wr3, t);
            acc[nb] = t;
        }
    }
    float bj = b1[j];
    for (int nb = 0; nb < 8; nb++) {
        int n = nb0 + nb;
        if (n < N_NODES) {
            float vv = acc[nb] + bj;
            h[(size_t)n * D_H + j] = vv > 0.0f ? vv : expm1f(vv);
        }
    }
}

// ---------------- en (fp32) + enb (bf16) = h/max(||h||,eps); copy h to output ----------------
__global__ void norm_kernel(const float* __restrict__ h, float* __restrict__ en,
                            unsigned short* __restrict__ enb, float* __restrict__ outh) {
    int wid = threadIdx.x >> 6, lane = threadIdx.x & 63;
    int n = blockIdx.x * 4 + wid;
    if (n >= N_NODES) return;
    float4 v = *(const float4*)&h[(size_t)n * D_H + lane * 4];
    float ss = v.x * v.x + v.y * v.y + v.z * v.z + v.w * v.w;
    for (int o = 32; o; o >>= 1) ss += __shfl_xor(ss, o);
    float inv = 1.0f / fmaxf(sqrtf(ss), 1e-8f);
    float e[4] = {v.x * inv, v.y * inv, v.z * inv, v.w * inv};
    *(float4*)&en[(size_t)n * D_H + lane * 4] = make_float4(e[0], e[1], e[2], e[3]);
    unsigned int p[4];
    #pragma unroll
    for (int k = 0; k < 4; k++) {
        unsigned int ub = __float_as_uint(e[k]);
        p[k] = (ub + 0x7FFFu + ((ub >> 16) & 1u)) >> 16;   // RNE to bf16
    }
    uint2 packed = make_uint2(p[0] | (p[1] << 16), p[2] | (p[3] << 16));
    *(uint2*)&enb[(size_t)n * D_H + lane * 4] = packed;
    *(float4*)&outh[(size_t)n * D_H + lane * 4] = v;
}

// ---------------- lcls = log_softmax(elu(agg2/cnt @ W2_l^T + b2 + h @ W2_r^T)) (R1-proven) ----------------
__global__ void lc_kernel(const float* __restrict__ h, const float* __restrict__ agg2,
        const float* __restrict__ cnt, const float* __restrict__ W2lT,
        const float* __restrict__ W2rT, const float* __restrict__ b2,
        float* __restrict__ lcls) {
    __shared__ float sa[4][D_H];
    __shared__ float sh[4][D_H];
    int wid = threadIdx.x >> 6, lane = threadIdx.x & 63;
    int n = blockIdx.x * 4 + wid;
    bool valid = (n < N_NODES);
    if (valid) {
        float inv = 1.0f / fmaxf(cnt[n], 1.0f);
        float4 a = *(const float4*)&agg2[(size_t)n * D_H + lane * 4];
        a.x *= inv; a.y *= inv; a.z *= inv; a.w *= inv;
        *(float4*)&sa[wid][lane * 4] = a;
        float4 hh = *(const float4*)&h[(size_t)n * D_H + lane * 4];
        *(float4*)&sh[wid][lane * 4] = hh;
    }
    __syncthreads();
    int c = lane;
    float acc = 0.0f;
    if (valid && c < NCLS) {
        for (int i = 0; i < D_H; i++) {
            acc = fmaf(sa[wid][i], W2lT[(size_t)i * NCLS + c], acc);
            acc = fmaf(sh[wid][i], W2rT[(size_t)i * NCLS + c], acc);
        }
        acc += b2[c];
        acc = acc > 0.0f ? acc : expm1f(acc);
    }
    float v = (valid && c < NCLS) ? acc : -INFINITY;
    float m = v;
    for (int o = 32; o; o >>= 1) m = fmaxf(m, __shfl_xor(m, o));
    float ex = (valid && c < NCLS) ? expf(v - m) : 0.0f;
    float s = ex;
    for (int o = 32; o; o >>= 1) s += __shfl_xor(s, o);
    if (valid && c < NCLS) lcls[(size_t)n * NCLS + c] = v - m - logf(s);
}

// ---------------- MFMA bf16 prefilter: per-lane top-8 candidate indices ----------------
// Orientation (swapped operands): D(lane,q) = sim[rb*16+(l&15)][cbase+(l>>4)*4+q]
__global__ __launch_bounds__(256) void sim_topk_kernel(const unsigned short* __restrict__ enb,
        const float* __restrict__ mask, int* __restrict__ pi) {
    int rb = blockIdx.x >> 1, cs = blockIdx.x & 1;
    int tid = threadIdx.x;
    int w = tid >> 6, l = tid & 63;
    int l15 = l & 15, lh = l >> 4;          // lh: 0..3
    int r = rb * 16 + l15;                  // this lane's sim row (r <= 9999)

    // B fragments: the block's own 16 rows of en, full K=256
    bf16x8 bfr[8];
    const unsigned short* brow = enb + (size_t)r * D_H + 8 * lh;
    #pragma unroll
    for (int ks = 0; ks < 8; ks++) bfr[ks] = *(const bf16x8*)(brow + ks * 32);

    float tv[SLOTS]; int ti[SLOTS];
    #pragma unroll
    for (int k = 0; k < SLOTS; k++) { tv[k] = -INFINITY; ti[k] = 0; }

    int stream = cs * 4 + w;                // 0..7
    const float* mrow = mask + (size_t)r * N_NODES;

    for (int f = stream; f < NFRAG; f += NSTREAM) {
        int cbase = f * 16;
        const unsigned short* arow = enb + (size_t)(cbase + l15) * D_H + 8 * lh;
        f32x4 acc = {0.f, 0.f, 0.f, 0.f};
        #pragma unroll
        for (int ks = 0; ks < 8; ks++) {
            bf16x8 af = *(const bf16x8*)(arow + ks * 32);
            acc = __builtin_amdgcn_mfma_f32_16x16x32_bf16(af, bfr[ks], acc, 0, 0, 0);
        }
        int c0 = cbase + lh * 4;
        float4 mm = *(const float4*)&mrow[c0];
        float vv[4];
        vv[0] = acc[0] * mm.x; vv[1] = acc[1] * mm.y;
        vv[2] = acc[2] * mm.z; vv[3] = acc[3] * mm.w;
        #pragma unroll
        for (int j = 0; j < 4; j++) {
            float v = vv[j]; int c = c0 + j;
            // predicated insert into sorted-ascending top-8 (tv[0] = 8th best)
            if ((v > tv[0]) || (v == tv[0] && c < ti[0])) {
                #pragma unroll
                for (int k = 0; k < SLOTS - 1; k++) {
                    bool sh = (tv[k+1] < v) || (tv[k+1] == v && ti[k+1] > c);
                    bool he = (tv[k]   < v) || (tv[k]   == v && ti[k]   > c);
                    float nv = sh ? tv[k+1] : (he ? v : tv[k]);
                    int   ni = sh ? ti[k+1] : (he ? c : ti[k]);
                    tv[k] = nv; ti[k] = ni;
                }
                bool he7 = (tv[SLOTS-1] < v) || (tv[SLOTS-1] == v && ti[SLOTS-1] > c);
                tv[SLOTS-1] = he7 ? v : tv[SLOTS-1];
                ti[SLOTS-1] = he7 ? c : ti[SLOTS-1];
            }
        }
    }

    int slot = (stream * 4 + lh) * SLOTS;   // 0..255 in steps of 8
    int* pip = pi + (size_t)r * CPR + slot;
    #pragma unroll
    for (int k = 0; k < SLOTS; k++) pip[k] = ti[k];
}

// ---------------- exact fp32 rescore of 256 candidates -> top-16 -> fusion -> blend ----------------
__global__ __launch_bounds__(256) void rescore_merge_kernel(const float* __restrict__ en,
        const float* __restrict__ mask, const int* __restrict__ pi,
        const int* __restrict__ y, const float* __restrict__ lcls, float* __restrict__ out) {
    __shared__ float sen[4][D_H];
    int wid = threadIdx.x >> 6, lane = threadIdx.x & 63;
    int r = blockIdx.x * 4 + wid;            // grid = 2500 blocks exactly -> r < 10000 always
    // stage this row's en into LDS
    *(float4*)&sen[wid][lane * 4] = *(const float4*)&en[(size_t)r * D_H + lane * 4];
    __syncthreads();

    int4 cc = *(const int4*)&pi[(size_t)r * CPR + lane * 4];
    int ci[4] = {cc.x, cc.y, cc.z, cc.w};
    float cv[4];
    const float* mrow = mask + (size_t)r * N_NODES;
    #pragma unroll
    for (int u = 0; u < 4; u++) {
        int c = ci[u];
        c = (c >= 0 && c < N_NODES) ? c : 0;
        ci[u] = c;
        const float* erow = &en[(size_t)c * D_H];
        float dot = 0.0f;
        for (int k = 0; k < D_H; k += 4) {
            float4 e = *(const float4*)&erow[k];
            dot = fmaf(sen[wid][k + 0], e.x, dot);
            dot = fmaf(sen[wid][k + 1], e.y, dot);
            dot = fmaf(sen[wid][k + 2], e.z, dot);
            dot = fmaf(sen[wid][k + 3], e.w, dot);
        }
        cv[u] = dot * mrow[c];
    }

    // top-16 by (value desc, index asc); indices are unique per row
    float fc = 0.0f;
    for (int t = 0; t < KTOP; t++) {
        float bv = cv[0]; int bi = ci[0];
        #pragma unroll
        for (int u = 1; u < 4; u++) {
            bool bet = (cv[u] > bv) || (cv[u] == bv && ci[u] < bi);
            bv = bet ? cv[u] : bv; bi = bet ? ci[u] : bi;
        }
        float rv = bv; int ri = bi;
        #pragma unroll
        for (int o = 1; o < 64; o <<= 1) {
            float ov = __shfl_xor(rv, o); int oi = __shfl_xor(ri, o);
            bool bet = (ov > rv) || (ov == rv && oi < ri);
            rv = bet ? ov : rv; ri = bet ? oi : ri;
        }
        #pragma unroll
        for (int u = 0; u < 4; u++) {
            bool hit = (ci[u] == ri);
            cv[u] = hit ? -INFINITY : cv[u];
        }
        int ris = (ri >= 0 && ri < N_NODES) ? ri : 0;
        int lbl = y[ris];
        if (lane == lbl) fc += expf(rv);
    }
    float fval = (lane < NCLS) ? fc : -INFINITY;
    float m = fval;
    for (int o = 32; o; o >>= 1) m = fmaxf(m, __shfl_xor(m, o));
    float ex = (lane < NCLS) ? expf(fval - m) : 0.0f;
    float s = ex;
    for (int o = 32; o; o >>= 1) s += __shfl_xor(s, o);
    if (lane < NCLS)
        out[(size_t)r * NCLS + lane] = 0.5f * lcls[(size_t)r * NCLS + lane]
                                     + 0.5f * (fval - m - logf(s));
}

extern "C" void kernel_launch(void* const* d_in, const int* in_sizes, int n_in,
                              void* d_out, int out_size, void* d_ws, size_t ws_size,
                              hipStream_t stream) {
    const float* x    = (const float*)d_in[0];
    const int*   ei   = (const int*)  d_in[1];
    const int*   y    = (const int*)  d_in[2];
    const float* mask = (const float*)d_in[3];
    const float* W1_l = (const float*)d_in[4];
    const float* b1   = (const float*)d_in[5];
    const float* W1_r = (const float*)d_in[6];
    const float* W2_l = (const float*)d_in[7];
    const float* b2   = (const float*)d_in[8];
    const float* W2_r = (const float*)d_in[9];

    float* out   = (float*)d_out;
    float* out_h = out + (size_t)N_NODES * NCLS;

    float* w    = (float*)d_ws;
    float* cnt  = w;                                     // 10240
    float* agg1 = w + 10240;                             // N*512
    float* agg2 = agg1 + (size_t)N_NODES * D_IN;         // N*256
    float* h    = agg2 + (size_t)N_NODES * D_H;          // N*256
    float* en   = h    + (size_t)N_NODES * D_H;          // N*256 fp32
    unsigned short* enb = (unsigned short*)(en + (size_t)N_NODES * D_H);  // N*256 bf16
    float* lcls = (float*)(enb + (size_t)N_NODES * D_H); // N*40
    float* W1lT = lcls + (size_t)N_NODES * NCLS;
    float* W1rT = W1lT + (size_t)D_IN * D_H;
    float* W2lT = W1rT + (size_t)D_IN * D_H;
    float* W2rT = W2lT + (size_t)D_H * NCLS;
    int*   pi   = (int*)(W2rT + (size_t)D_H * NCLS);     // N*256

    const int* src = ei;
    const int* dst = ei + NEDGE;

    // zero cnt + agg1 + agg2 (contiguous)
    size_t zbytes = (size_t)(10240 + (size_t)N_NODES * D_IN + (size_t)N_NODES * D_H) * sizeof(float);
    hipMemsetAsync(d_ws, 0, zbytes, stream);

    transpose_kernel<<<(D_H * D_IN + 255) / 256, 256, 0, stream>>>(
        W1_l, W1_r, W2_l, W2_r, W1lT, W1rT, W2lT, W2rT);
    count_kernel<<<(NEDGE + 255) / 256, 256, 0, stream>>>(dst, cnt);
    scatter1_kernel<<<NEDGE * (D_IN / 4) / 256, 256, 0, stream>>>(x, src, dst, agg1);
    hidden_kernel<<<(N_NODES + 7) / 8, 256, 0, stream>>>(x, agg1, cnt, W1lT, W1rT, b1, h);
    norm_kernel<<<(N_NODES + 3) / 4, 256, 0, stream>>>(h, en, enb, out_h);
    scatter2_kernel<<<NEDGE * (D_H / 4) / 256, 256, 0, stream>>>(h, src, dst, agg2);
    lc_kernel<<<(N_NODES + 3) / 4, 256, 0, stream>>>(h, agg2, cnt, W2lT, W2rT, b2, lcls);
    sim_topk_kernel<<<NFRAG * CSPL, 256, 0, stream>>>(enb, mask, pi);
    rescore_merge_kernel<<<(N_NODES + 3) / 4, 256, 0, stream>>>(en, mask, pi, y, lcls, out);
}

// Round 5
// 1046.939 us; speedup vs baseline: 12.4279x; 2.4809x over previous
//
#include <hip/hip_runtime.h>
#include <math.h>

#define N_NODES 10000
#define D_IN    512
#define D_H     256
#define NCLS    40
#define NEDGE   160000
#define KTOP    16
#define NFRAG   625            // 10000 / 16 column fragments
#define CSPL    2              // column splits (blocks per row-tile)
#define NSTREAM 8              // CSPL * 4 waves
#define SLOTS   8              // per-lane-group top-8
#define CPR     (NSTREAM * 4 * SLOTS)   // candidates per row = 256

typedef __attribute__((ext_vector_type(8))) short bf16x8;
typedef __attribute__((ext_vector_type(4))) float f32x4;

// ---------------- transpose weights ----------------
__global__ void transpose_kernel(const float* __restrict__ W1_l, const float* __restrict__ W1_r,
                                 const float* __restrict__ W2_l, const float* __restrict__ W2_r,
                                 float* __restrict__ W1lT, float* __restrict__ W1rT,
                                 float* __restrict__ W2lT, float* __restrict__ W2rT) {
    int i = blockIdx.x * 256 + threadIdx.x;
    if (i < D_H * D_IN) {
        int r = i / D_IN, c = i % D_IN;
        W1lT[(size_t)c * D_H + r] = W1_l[i];
        W1rT[(size_t)c * D_H + r] = W1_r[i];
    }
    if (i < NCLS * D_H) {
        int r = i / D_H, c = i % D_H;
        W2lT[(size_t)c * NCLS + r] = W2_l[i];
        W2rT[(size_t)c * NCLS + r] = W2_r[i];
    }
}

// ---------------- degree count (int) ----------------
__global__ void count_kernel(const int* __restrict__ dst, int* __restrict__ cnt) {
    int e = blockIdx.x * 256 + threadIdx.x;
    if (e < NEDGE) {
        int d = dst[e];
        d = (d >= 0 && d < N_NODES) ? d : 0;
        atomicAdd(&cnt[d], 1);
    }
}

// ---------------- prefix scan -> rowptr, cursor ----------------
__global__ void prefix_kernel(const int* __restrict__ cnt, int* __restrict__ rowptr,
                              int* __restrict__ cursor) {
    __shared__ int sp[256];
    int t = threadIdx.x;
    int b0 = t * 40;
    int e0 = (b0 + 40 < N_NODES) ? b0 + 40 : N_NODES;
    int s = 0;
    for (int i = b0; i < e0; i++) s += cnt[i];
    sp[t] = s;
    __syncthreads();
    for (int o = 1; o < 256; o <<= 1) {
        int add = (t >= o) ? sp[t - o] : 0;
        __syncthreads();
        sp[t] += add;
        __syncthreads();
    }
    int run = sp[t] - s;     // exclusive prefix
    for (int i = b0; i < e0; i++) {
        rowptr[i] = run; cursor[i] = run; run += cnt[i];
    }
    if (t == 255) rowptr[N_NODES] = run;
}

// ---------------- bucket edges by dst ----------------
__global__ void bucket_kernel(const int* __restrict__ src, const int* __restrict__ dst,
                              int* __restrict__ cursor, int* __restrict__ nbr) {
    int e = blockIdx.x * 256 + threadIdx.x;
    if (e < NEDGE) {
        int d = dst[e];
        d = (d >= 0 && d < N_NODES) ? d : 0;
        int p = atomicAdd(&cursor[d], 1);
        if (p >= 0 && p < NEDGE) {
            int s = src[e];
            nbr[p] = (s >= 0 && s < N_NODES) ? s : 0;
        }
    }
}

// ---------------- xw1 = x @ W1_l^T ; xwr = x @ W1_r^T ----------------
__global__ __launch_bounds__(256) void proj1_kernel(const float* __restrict__ x,
        const float* __restrict__ W1lT, const float* __restrict__ W1rT,
        float* __restrict__ xw1, float* __restrict__ xwr) {
    __shared__ float sx[8][D_IN];
    int tid = threadIdx.x;
    int nb0 = blockIdx.x * 8;
    #pragma unroll
    for (int u = 0; u < 4; u++) {
        int s = tid + u * 256;          // 0..1023
        int nb = s >> 7;                // 0..7
        int c4 = (s & 127) << 2;        // 0..508
        int n = nb0 + nb;
        float4 v = make_float4(0.f, 0.f, 0.f, 0.f);
        if (n < N_NODES) v = *(const float4*)&x[(size_t)n * D_IN + c4];
        *(float4*)&sx[nb][c4] = v;
    }
    __syncthreads();
    int j = tid;
    float accl[8] = {0,0,0,0,0,0,0,0};
    float accr[8] = {0,0,0,0,0,0,0,0};
    for (int i = 0; i < D_IN; i += 4) {
        float wl0 = W1lT[(size_t)(i + 0) * D_H + j];
        float wl1 = W1lT[(size_t)(i + 1) * D_H + j];
        float wl2 = W1lT[(size_t)(i + 2) * D_H + j];
        float wl3 = W1lT[(size_t)(i + 3) * D_H + j];
        float wr0 = W1rT[(size_t)(i + 0) * D_H + j];
        float wr1 = W1rT[(size_t)(i + 1) * D_H + j];
        float wr2 = W1rT[(size_t)(i + 2) * D_H + j];
        float wr3 = W1rT[(size_t)(i + 3) * D_H + j];
        #pragma unroll
        for (int nb = 0; nb < 8; nb++) {
            float4 xx = *(const float4*)&sx[nb][i];
            float tl = accl[nb], tr = accr[nb];
            tl = fmaf(xx.x, wl0, tl); tl = fmaf(xx.y, wl1, tl);
            tl = fmaf(xx.z, wl2, tl); tl = fmaf(xx.w, wl3, tl);
            tr = fmaf(xx.x, wr0, tr); tr = fmaf(xx.y, wr1, tr);
            tr = fmaf(xx.z, wr2, tr); tr = fmaf(xx.w, wr3, tr);
            accl[nb] = tl; accr[nb] = tr;
        }
    }
    for (int nb = 0; nb < 8; nb++) {
        int n = nb0 + nb;
        if (n < N_NODES) {
            xw1[(size_t)n * D_H + j] = accl[nb];
            xwr[(size_t)n * D_H + j] = accr[nb];
        }
    }
}

// ---------------- h = elu(mean(xw1[nbr]) + b1 + xwr) ----------------
__global__ void gather_h_kernel(const float* __restrict__ xw1, const float* __restrict__ xwr,
                                const int* __restrict__ nbr, const int* __restrict__ rowptr,
                                const int* __restrict__ cnt, const float* __restrict__ b1,
                                float* __restrict__ h) {
    int wid = threadIdx.x >> 6, lane = threadIdx.x & 63;
    int n = blockIdx.x * 4 + wid;
    if (n >= N_NODES) return;
    int st = rowptr[n], deg = cnt[n];
    float a[4] = {0,0,0,0};
    for (int j = 0; j < deg; j++) {
        int s = nbr[st + j];
        float4 v = *(const float4*)&xw1[(size_t)s * D_H + lane * 4];
        a[0] += v.x; a[1] += v.y; a[2] += v.z; a[3] += v.w;
    }
    float inv = 1.0f / fmaxf((float)deg, 1.0f);
    float4 r = *(const float4*)&xwr[(size_t)n * D_H + lane * 4];
    float4 bb = *(const float4*)&b1[lane * 4];
    float o0 = a[0] * inv + bb.x + r.x;
    float o1 = a[1] * inv + bb.y + r.y;
    float o2 = a[2] * inv + bb.z + r.z;
    float o3 = a[3] * inv + bb.w + r.w;
    o0 = o0 > 0.f ? o0 : expm1f(o0);
    o1 = o1 > 0.f ? o1 : expm1f(o1);
    o2 = o2 > 0.f ? o2 : expm1f(o2);
    o3 = o3 > 0.f ? o3 : expm1f(o3);
    *(float4*)&h[(size_t)n * D_H + lane * 4] = make_float4(o0, o1, o2, o3);
}

// ---------------- en (fp32) + enb (bf16) = h/max(||h||,eps); copy h to output ----------------
__global__ void norm_kernel(const float* __restrict__ h, float* __restrict__ en,
                            unsigned short* __restrict__ enb, float* __restrict__ outh) {
    int wid = threadIdx.x >> 6, lane = threadIdx.x & 63;
    int n = blockIdx.x * 4 + wid;
    if (n >= N_NODES) return;
    float4 v = *(const float4*)&h[(size_t)n * D_H + lane * 4];
    float ss = v.x * v.x + v.y * v.y + v.z * v.z + v.w * v.w;
    for (int o = 32; o; o >>= 1) ss += __shfl_xor(ss, o);
    float inv = 1.0f / fmaxf(sqrtf(ss), 1e-8f);
    float e[4] = {v.x * inv, v.y * inv, v.z * inv, v.w * inv};
    *(float4*)&en[(size_t)n * D_H + lane * 4] = make_float4(e[0], e[1], e[2], e[3]);
    unsigned int p[4];
    #pragma unroll
    for (int k = 0; k < 4; k++) {
        unsigned int ub = __float_as_uint(e[k]);
        p[k] = (ub + 0x7FFFu + ((ub >> 16) & 1u)) >> 16;   // RNE to bf16
    }
    uint2 packed = make_uint2(p[0] | (p[1] << 16), p[2] | (p[3] << 16));
    *(uint2*)&enb[(size_t)n * D_H + lane * 4] = packed;
    *(float4*)&outh[(size_t)n * D_H + lane * 4] = v;
}

// ---------------- hwl = h @ W2_l^T ; hwr = h @ W2_r^T ----------------
__global__ void proj2_kernel(const float* __restrict__ h, const float* __restrict__ W2lT,
                             const float* __restrict__ W2rT, float* __restrict__ hwl,
                             float* __restrict__ hwr) {
    __shared__ float sh[4][D_H];
    int wid = threadIdx.x >> 6, lane = threadIdx.x & 63;
    int n = blockIdx.x * 4 + wid;
    bool valid = (n < N_NODES);
    if (valid)
        *(float4*)&sh[wid][lane * 4] = *(const float4*)&h[(size_t)n * D_H + lane * 4];
    __syncthreads();
    if (!valid || lane >= NCLS) return;
    float al = 0.f, ar = 0.f;
    for (int i = 0; i < D_H; i++) {
        float hv = sh[wid][i];
        al = fmaf(hv, W2lT[(size_t)i * NCLS + lane], al);
        ar = fmaf(hv, W2rT[(size_t)i * NCLS + lane], ar);
    }
    hwl[(size_t)n * NCLS + lane] = al;
    hwr[(size_t)n * NCLS + lane] = ar;
}

// ---------------- lcls = log_softmax(elu(mean(hwl[nbr]) + b2 + hwr)) ----------------
__global__ void gather_lc_kernel(const float* __restrict__ hwl, const float* __restrict__ hwr,
                                 const int* __restrict__ nbr, const int* __restrict__ rowptr,
                                 const int* __restrict__ cnt, const float* __restrict__ b2,
                                 float* __restrict__ lcls) {
    int wid = threadIdx.x >> 6, lane = threadIdx.x & 63;
    int n = blockIdx.x * 4 + wid;
    if (n >= N_NODES) return;
    int st = rowptr[n], deg = cnt[n];
    float a = 0.f;
    if (lane < NCLS) {
        for (int j = 0; j < deg; j++) {
            int s = nbr[st + j];
            a += hwl[(size_t)s * NCLS + lane];
        }
    }
    float inv = 1.0f / fmaxf((float)deg, 1.0f);
    float v;
    if (lane < NCLS) {
        v = a * inv + b2[lane] + hwr[(size_t)n * NCLS + lane];
        v = v > 0.f ? v : expm1f(v);
    } else {
        v = -INFINITY;
    }
    float m = v;
    for (int o = 32; o; o >>= 1) m = fmaxf(m, __shfl_xor(m, o));
    float ex = (lane < NCLS) ? expf(v - m) : 0.0f;
    float s = ex;
    for (int o = 32; o; o >>= 1) s += __shfl_xor(s, o);
    if (lane < NCLS) lcls[(size_t)n * NCLS + lane] = v - m - logf(s);
}

// ---------------- MFMA bf16 prefilter: per-lane top-8 candidate indices ----------------
// Orientation (swapped operands): D(lane,q) = sim[rb*16+(l&15)][cbase+(l>>4)*4+q]
__global__ __launch_bounds__(256) void sim_topk_kernel(const unsigned short* __restrict__ enb,
        const float* __restrict__ mask, int* __restrict__ pi) {
    int rb = blockIdx.x >> 1, cs = blockIdx.x & 1;
    int tid = threadIdx.x;
    int w = tid >> 6, l = tid & 63;
    int l15 = l & 15, lh = l >> 4;          // lh: 0..3
    int r = rb * 16 + l15;                  // this lane's sim row (r <= 9999)

    bf16x8 bfr[8];
    const unsigned short* brow = enb + (size_t)r * D_H + 8 * lh;
    #pragma unroll
    for (int ks = 0; ks < 8; ks++) bfr[ks] = *(const bf16x8*)(brow + ks * 32);

    float tv[SLOTS]; int ti[SLOTS];
    #pragma unroll
    for (int k = 0; k < SLOTS; k++) { tv[k] = -INFINITY; ti[k] = 0; }

    int stream = cs * 4 + w;                // 0..7
    const float* mrow = mask + (size_t)r * N_NODES;

    for (int f = stream; f < NFRAG; f += NSTREAM) {
        int cbase = f * 16;
        const unsigned short* arow = enb + (size_t)(cbase + l15) * D_H + 8 * lh;
        f32x4 acc = {0.f, 0.f, 0.f, 0.f};
        #pragma unroll
        for (int ks = 0; ks < 8; ks++) {
            bf16x8 af = *(const bf16x8*)(arow + ks * 32);
            acc = __builtin_amdgcn_mfma_f32_16x16x32_bf16(af, bfr[ks], acc, 0, 0, 0);
        }
        int c0 = cbase + lh * 4;
        float4 mm = *(const float4*)&mrow[c0];
        float vv[4];
        vv[0] = acc[0] * mm.x; vv[1] = acc[1] * mm.y;
        vv[2] = acc[2] * mm.z; vv[3] = acc[3] * mm.w;
        #pragma unroll
        for (int j = 0; j < 4; j++) {
            float v = vv[j]; int c = c0 + j;
            if ((v > tv[0]) || (v == tv[0] && c < ti[0])) {
                #pragma unroll
                for (int k = 0; k < SLOTS - 1; k++) {
                    bool sh = (tv[k+1] < v) || (tv[k+1] == v && ti[k+1] > c);
                    bool he = (tv[k]   < v) || (tv[k]   == v && ti[k]   > c);
                    float nv = sh ? tv[k+1] : (he ? v : tv[k]);
                    int   ni = sh ? ti[k+1] : (he ? c : ti[k]);
                    tv[k] = nv; ti[k] = ni;
                }
                bool he7 = (tv[SLOTS-1] < v) || (tv[SLOTS-1] == v && ti[SLOTS-1] > c);
                tv[SLOTS-1] = he7 ? v : tv[SLOTS-1];
                ti[SLOTS-1] = he7 ? c : ti[SLOTS-1];
            }
        }
    }

    int slot = (stream * 4 + lh) * SLOTS;   // 0..255 in steps of 8
    int* pip = pi + (size_t)r * CPR + slot;
    #pragma unroll
    for (int k = 0; k < SLOTS; k++) pip[k] = ti[k];
}

// ---------------- exact fp32 rescore of 256 candidates -> top-16 -> fusion -> blend ----------------
__global__ __launch_bounds__(256) void rescore_merge_kernel(const float* __restrict__ en,
        const float* __restrict__ mask, const int* __restrict__ pi,
        const int* __restrict__ y, const float* __restrict__ lcls, float* __restrict__ out) {
    __shared__ float sen[4][D_H];
    int wid = threadIdx.x >> 6, lane = threadIdx.x & 63;
    int r = blockIdx.x * 4 + wid;
    if (r >= N_NODES) return;
    *(float4*)&sen[wid][lane * 4] = *(const float4*)&en[(size_t)r * D_H + lane * 4];
    __syncthreads();

    int4 cc = *(const int4*)&pi[(size_t)r * CPR + lane * 4];
    int ci[4] = {cc.x, cc.y, cc.z, cc.w};
    float cv[4];
    const float* mrow = mask + (size_t)r * N_NODES;
    #pragma unroll
    for (int u = 0; u < 4; u++) {
        int c = ci[u];
        c = (c >= 0 && c < N_NODES) ? c : 0;
        ci[u] = c;
        const float* erow = &en[(size_t)c * D_H];
        float dot = 0.0f;
        for (int k = 0; k < D_H; k += 4) {
            float4 e = *(const float4*)&erow[k];
            dot = fmaf(sen[wid][k + 0], e.x, dot);
            dot = fmaf(sen[wid][k + 1], e.y, dot);
            dot = fmaf(sen[wid][k + 2], e.z, dot);
            dot = fmaf(sen[wid][k + 3], e.w, dot);
        }
        cv[u] = dot * mrow[c];
    }

    float fc = 0.0f;
    for (int t = 0; t < KTOP; t++) {
        float bv = cv[0]; int bi = ci[0];
        #pragma unroll
        for (int u = 1; u < 4; u++) {
            bool bet = (cv[u] > bv) || (cv[u] == bv && ci[u] < bi);
            bv = bet ? cv[u] : bv; bi = bet ? ci[u] : bi;
        }
        float rv = bv; int ri = bi;
        #pragma unroll
        for (int o = 1; o < 64; o <<= 1) {
            float ov = __shfl_xor(rv, o); int oi = __shfl_xor(ri, o);
            bool bet = (ov > rv) || (ov == rv && oi < ri);
            rv = bet ? ov : rv; ri = bet ? oi : ri;
        }
        #pragma unroll
        for (int u = 0; u < 4; u++) {
            bool hit = (ci[u] == ri);
            cv[u] = hit ? -INFINITY : cv[u];
        }
        int ris = (ri >= 0 && ri < N_NODES) ? ri : 0;
        int lbl = y[ris];
        if (lane == lbl) fc += expf(rv);
    }
    float fval = (lane < NCLS) ? fc : -INFINITY;
    float m = fval;
    for (int o = 32; o; o >>= 1) m = fmaxf(m, __shfl_xor(m, o));
    float ex = (lane < NCLS) ? expf(fval - m) : 0.0f;
    float s = ex;
    for (int o = 32; o; o >>= 1) s += __shfl_xor(s, o);
    if (lane < NCLS)
        out[(size_t)r * NCLS + lane] = 0.5f * lcls[(size_t)r * NCLS + lane]
                                     + 0.5f * (fval - m - logf(s));
}

extern "C" void kernel_launch(void* const* d_in, const int* in_sizes, int n_in,
                              void* d_out, int out_size, void* d_ws, size_t ws_size,
                              hipStream_t stream) {
    const float* x    = (const float*)d_in[0];
    const int*   ei   = (const int*)  d_in[1];
    const int*   y    = (const int*)  d_in[2];
    const float* mask = (const float*)d_in[3];
    const float* W1_l = (const float*)d_in[4];
    const float* b1   = (const float*)d_in[5];
    const float* W1_r = (const float*)d_in[6];
    const float* W2_l = (const float*)d_in[7];
    const float* b2   = (const float*)d_in[8];
    const float* W2_r = (const float*)d_in[9];

    float* out   = (float*)d_out;
    float* out_h = out + (size_t)N_NODES * NCLS;

    int*   cnt    = (int*)d_ws;                       // 10240
    int*   rowptr = cnt + 10240;                      // 10304
    int*   cursor = rowptr + 10304;                   // 10240
    int*   nbr    = cursor + 10240;                   // 160256
    float* xw1    = (float*)(nbr + 160256);           // N*256
    float* xwr    = xw1 + (size_t)N_NODES * D_H;      // N*256
    float* h      = xwr + (size_t)N_NODES * D_H;      // N*256
    float* en     = h   + (size_t)N_NODES * D_H;      // N*256
    unsigned short* enb = (unsigned short*)(en + (size_t)N_NODES * D_H);  // N*256 bf16
    float* lcls   = (float*)(enb + (size_t)N_NODES * D_H);                // N*40
    float* hwl    = lcls + (size_t)N_NODES * NCLS;    // N*40
    float* hwr    = hwl + (size_t)N_NODES * NCLS;     // N*40
    float* W1lT   = hwr + (size_t)N_NODES * NCLS;
    float* W1rT   = W1lT + (size_t)D_IN * D_H;
    float* W2lT   = W1rT + (size_t)D_IN * D_H;
    float* W2rT   = W2lT + (size_t)D_H * NCLS;
    int*   pi     = (int*)(W2rT + (size_t)D_H * NCLS);  // N*256

    const int* src = ei;
    const int* dst = ei + NEDGE;

    hipMemsetAsync(cnt, 0, 10240 * sizeof(int), stream);

    transpose_kernel<<<(D_H * D_IN + 255) / 256, 256, 0, stream>>>(
        W1_l, W1_r, W2_l, W2_r, W1lT, W1rT, W2lT, W2rT);
    count_kernel<<<(NEDGE + 255) / 256, 256, 0, stream>>>(dst, cnt);
    prefix_kernel<<<1, 256, 0, stream>>>(cnt, rowptr, cursor);
    bucket_kernel<<<(NEDGE + 255) / 256, 256, 0, stream>>>(src, dst, cursor, nbr);
    proj1_kernel<<<(N_NODES + 7) / 8, 256, 0, stream>>>(x, W1lT, W1rT, xw1, xwr);
    gather_h_kernel<<<(N_NODES + 3) / 4, 256, 0, stream>>>(xw1, xwr, nbr, rowptr, cnt, b1, h);
    norm_kernel<<<(N_NODES + 3) / 4, 256, 0, stream>>>(h, en, enb, out_h);
    proj2_kernel<<<(N_NODES + 3) / 4, 256, 0, stream>>>(h, W2lT, W2rT, hwl, hwr);
    gather_lc_kernel<<<(N_NODES + 3) / 4, 256, 0, stream>>>(hwl, hwr, nbr, rowptr, cnt, b2, lcls);
    sim_topk_kernel<<<NFRAG * CSPL, 256, 0, stream>>>(enb, mask, pi);
    rescore_merge_kernel<<<(N_NODES + 3) / 4, 256, 0, stream>>>(en, mask, pi, y, lcls, out);
}